// Round 8
// baseline (217.943 us; speedup 1.0000x reference)
//
#include <hip/hip_runtime.h>
#include <hip/hip_bf16.h>

// Shapes (fixed by the reference):
//   edges     [E=4096, 2]        int32
//   neigh_idx [N=100000, K=10]   int32
//   features  [N, 256]           f32
//   W1        [128, 256]         f32
//   W2        [128, 128]         f32
//   Wc        [2, 128]           f32
// out = [E, 2] f32
//
// Pipeline:
//   fcvt   : features f32 -> fb16 bf16 (row-swizzled), W1 -> w1b bf16, M2 = Wc@W2
//   gemm_z : z = fb16 @ w1b^T via MFMA; staging = linear global_load_lds (async DMA,
//            zero VALU) of the pre-swizzled rows; ds_read uses matching XOR swizzle.
//   aggregate: h1m/pool/classify per edge (unchanged from R3: paired-row uint2 gathers).
//
// R6 kernel, third submission (two GPU-acquisition timeouts): R5 counters
//     showed gemm_z latency-bound (15% HBM, MfmaUtil 3.7%, VGPR=52 -> shallow
//     load pipeline in the f32->bf16 staging chain). Split the conversion into
//     a streaming kernel and stage the GEMM tile with global_load_lds.
//     Swizzle discipline (rule 21): fcvt writes slot^=(row&7) on 16B slots
//     within each 512B row (inverse-swizzled SOURCE); gemm stages LINEARLY
//     into LDS and applies the same XOR on the ds_read side.

typedef __bf16 bf16x8 __attribute__((ext_vector_type(8)));
typedef float f32x4 __attribute__((ext_vector_type(4)));

#define FEAT 256
#define EMB  128
#define KNB  10
#define BM   64    // gemm M-tile rows (LDS = 64*512B = 32 KB)

__device__ inline unsigned short f2b(float f) {
  unsigned int u = __float_as_uint(f);
  unsigned int r = (u + 0x7fffu + ((u >> 16) & 1u)) >> 16;  // RNE
  return (unsigned short)r;
}
__device__ inline float b2f(unsigned int s) {
  return __uint_as_float(s << 16);
}

__device__ __forceinline__ void async_ld16(unsigned short* lds, const unsigned short* g) {
  // 16B global -> LDS direct (dest = wave-uniform base + lane*16)
  __builtin_amdgcn_global_load_lds(
      (const __attribute__((address_space(1))) unsigned int*)g,
      (__attribute__((address_space(3))) unsigned int*)lds, 16, 0, 0);
}

// ---- fcvt: streaming conversions + tiny M2 ------------------------------
// blocks [0, nbF)        : features -> fb16, 8 elems (16B) per thread,
//                          dst 16B-slot s stored at s^(row&7) within the row.
//                          rows >= N zero-filled (pad rows up to NPAD).
// blocks [nbF, nbF+16)   : W1 -> w1b (plain layout)
// block  nbF+16          : M2 = Wc @ W2  [2,128] f32

__global__ __launch_bounds__(256) void fcvt(
    const float* __restrict__ feat, const float* __restrict__ W1,
    const float* __restrict__ W2, const float* __restrict__ Wc,
    unsigned short* __restrict__ fb16, unsigned short* __restrict__ w1b,
    float* __restrict__ M2, int N, int nbF) {
  const int b = blockIdx.x;
  const int t = threadIdx.x;

  if (b < nbF) {
    int g = b * 256 + t;            // 16B-chunk id
    int r = g >> 5;                 // row (32 chunks of 8 bf16 per 256-col row)
    int s = g & 31;                 // logical slot
    float4 lo = make_float4(0.f, 0.f, 0.f, 0.f), hi = lo;
    if (r < N) {
      const float4* src = reinterpret_cast<const float4*>(&feat[(size_t)r * FEAT + s * 8]);
      lo = src[0]; hi = src[1];
    }
    ushort4 a, c;
    a.x = f2b(lo.x); a.y = f2b(lo.y); a.z = f2b(lo.z); a.w = f2b(lo.w);
    c.x = f2b(hi.x); c.y = f2b(hi.y); c.z = f2b(hi.z); c.w = f2b(hi.w);
    int sp = s ^ (r & 7);           // physical slot (inverse == forward; XOR involution)
    ushort4* dst = reinterpret_cast<ushort4*>(&fb16[(size_t)r * FEAT + sp * 8]);
    dst[0] = a; dst[1] = c;
  } else if (b < nbF + 16) {
    int g = (b - nbF) * 256 + t;    // 16B-chunk id over 128*256 = 32768 elems
    const float4* src = reinterpret_cast<const float4*>(&W1[g * 8]);
    float4 lo = src[0], hi = src[1];
    ushort4 a, c;
    a.x = f2b(lo.x); a.y = f2b(lo.y); a.z = f2b(lo.z); a.w = f2b(lo.w);
    c.x = f2b(hi.x); c.y = f2b(hi.y); c.z = f2b(hi.z); c.w = f2b(hi.w);
    ushort4* dst = reinterpret_cast<ushort4*>(&w1b[g * 8]);
    dst[0] = a; dst[1] = c;
  } else {
    int c = t >> 7, d = t & 127;
    float s = 0.f;
    for (int g = 0; g < EMB; ++g) s += Wc[c * EMB + g] * W2[g * EMB + d];
    M2[t] = s;
  }
}

// ---- gemm_z: z = fb16 @ w1b^T  (bf16 MFMA, f32 accum, bf16 out) ---------
// 512 threads (8 waves), BM=64 rows. Wave w owns cols [16w,16w+16).
// Stage: 4 rounds x (512 threads x 16B) = 32 KB, async global_load_lds,
// LDS linear (content row-swizzled by fcvt). MFMA reads apply slot^(row&7).

__global__ __launch_bounds__(512, 4) void gemm_z(
    const unsigned short* __restrict__ fb16, const unsigned short* __restrict__ w1b,
    unsigned short* __restrict__ z, int M) {
  __shared__ unsigned short As[BM * FEAT];   // 32 KB, linear

  const int wid  = threadIdx.x >> 6;
  const int lane = threadIdx.x & 63;
  const int m0   = blockIdx.x * BM;

  // B fragments, bf16-direct: lane holds col=(lane&15), k = kk*32 + (lane>>4)*8 + i
  const int col = wid * 16 + (lane & 15);
  const int kof = (lane >> 4) * 8;
  bf16x8 bfrag[8];
#pragma unroll
  for (int kk = 0; kk < 8; ++kk)
    bfrag[kk] = *reinterpret_cast<const bf16x8*>(&w1b[col * FEAT + kk * 32 + kof]);

  // async stage: per wave 1KB/round, per-lane global src, wave-uniform LDS base
  {
    const unsigned short* gbase = fb16 + (size_t)m0 * FEAT;
#pragma unroll
    for (int rnd = 0; rnd < 4; ++rnd) {
      int off = rnd * 4096 + wid * 512;            // ushort units (x2 = bytes)
      async_ld16(&As[off], &gbase[off + lane * 8]);
    }
  }
  __syncthreads();   // compiler drains vmcnt before barrier

  f32x4 acc[BM / 16] = {};
  const int arow = lane & 15;
  const int q    = lane >> 4;
#pragma unroll
  for (int mt = 0; mt < BM / 16; ++mt) {
    const int row = mt * 16 + arow;
    const int rb  = row * FEAT;
    const int rx  = row & 7;
#pragma unroll
    for (int kk = 0; kk < 8; ++kk) {
      int slot = (kk * 4 + q) ^ rx;                // swizzled 16B slot
      bf16x8 a = *reinterpret_cast<const bf16x8*>(&As[rb + slot * 8]);
      acc[mt] = __builtin_amdgcn_mfma_f32_16x16x32_bf16(a, bfrag[kk], acc[mt], 0, 0, 0);
    }
  }

  // D layout: col = lane&15, row = (lane>>4)*4 + reg   [m89-verified]
#pragma unroll
  for (int mt = 0; mt < BM / 16; ++mt) {
    int rbase = m0 + mt * 16 + q * 4;
#pragma unroll
    for (int r = 0; r < 4; ++r) {
      int row = rbase + r;
      if (row < M) z[(size_t)row * EMB + col] = f2b(acc[mt][r]);
    }
  }
}

// ---- per-edge aggregation + classifier (unchanged from R3) --------------

__global__ __launch_bounds__(128) void aggregate(
    const int* __restrict__ edges, const int* __restrict__ nidx,
    const unsigned short* __restrict__ z, const float* __restrict__ M2,
    float* __restrict__ out, int E) {
  __shared__ int   s_idx2[2][KNB];
  __shared__ int   s_idx1[2][KNB * KNB];
  __shared__ float s_pm[2][EMB];

  const int e = blockIdx.x;
  const int t = threadIdx.x;
  const int w = t >> 6;
  const int l = t & 63;
  const int h = l >> 5;
  const int q = l & 31;

  if (t < 2 * KNB) {
    int p = t / KNB, k = t % KNB;
    int v = edges[e * 2 + p];
    s_idx2[p][k] = nidx[(size_t)v * KNB + k];
  }
  __syncthreads();
  for (int i = t; i < 2 * KNB * KNB; i += 128) {
    int p = i / 100, r = i % 100;
    s_idx1[p][r] = nidx[(size_t)s_idx2[p][r / KNB] * KNB + (r % KNB)];
  }
  __syncthreads();

  float pooled[4] = {0.f, 0.f, 0.f, 0.f};
#pragma unroll
  for (int k = 0; k < KNB; ++k) {
    float a[4] = {0.f, 0.f, 0.f, 0.f};
#pragma unroll
    for (int jp = 0; jp < KNB / 2; ++jp) {
      int u = s_idx1[w][k * KNB + jp * 2 + h];
      uint2 v = *reinterpret_cast<const uint2*>(&z[(size_t)u * EMB + q * 4]);
      a[0] += b2f(v.x & 0xffffu); a[1] += b2f(v.x >> 16);
      a[2] += b2f(v.y & 0xffffu); a[3] += b2f(v.y >> 16);
    }
#pragma unroll
    for (int c = 0; c < 4; ++c) {
      float s = a[c] + __shfl_xor(a[c], 32);   // combine row parities: 10-row sum
      pooled[c] += fmaxf(s * 0.1f, 0.f);       // relu(mean_j)
    }
  }
  if (h == 0) {
#pragma unroll
    for (int c = 0; c < 4; ++c) s_pm[w][q * 4 + c] = pooled[c] * 0.1f;  // mean_k
  }
  __syncthreads();

  if (w == 0) {
    int d0 = 2 * l, d1 = 2 * l + 1;
    float p0 = 0.5f * (s_pm[0][d0] + s_pm[1][d0]);
    float p1 = 0.5f * (s_pm[0][d1] + s_pm[1][d1]);
    float s0 = p0 * M2[d0]       + p1 * M2[d1];
    float s1 = p0 * M2[EMB + d0] + p1 * M2[EMB + d1];
#pragma unroll
    for (int off = 32; off > 0; off >>= 1) {
      s0 += __shfl_down(s0, off);
      s1 += __shfl_down(s1, off);
    }
    if (l == 0) { out[e * 2 + 0] = s0; out[e * 2 + 1] = s1; }
  }
}

// ---- launcher -----------------------------------------------------------

extern "C" void kernel_launch(void* const* d_in, const int* in_sizes, int n_in,
                              void* d_out, int out_size, void* d_ws, size_t ws_size,
                              hipStream_t stream) {
  const int*   edges = (const int*)d_in[0];
  const int*   nidx  = (const int*)d_in[1];
  const float* feat  = (const float*)d_in[2];
  const float* W1    = (const float*)d_in[3];
  const float* W2    = (const float*)d_in[4];
  const float* Wc    = (const float*)d_in[5];
  float* out = (float*)d_out;

  const int N = in_sizes[2] / FEAT;   // 100000
  const int E = in_sizes[0] / 2;      // 4096

  const int mtiles = (N + BM - 1) / BM;   // 1563
  const int NPAD   = mtiles * BM;         // 100032

  // ws layout (~77 MB of the 400 MB ws): z | fb16 | w1b | M2
  char* ws = (char*)d_ws;
  unsigned short* z    = (unsigned short*)ws;                    // N*128 bf16
  unsigned short* fb16 = z + (size_t)N * EMB;                    // NPAD*256 bf16
  unsigned short* w1b  = fb16 + (size_t)NPAD * FEAT;             // 128*256 bf16
  float*          M2   = (float*)(w1b + EMB * FEAT);             // 2*128 f32

  const int nbF = NPAD / 8;               // feature-conversion blocks (12504)
  fcvt     <<<nbF + 16 + 1, 256, 0, stream>>>(feat, W1, W2, Wc, fb16, w1b, M2, N, nbF);
  gemm_z   <<<mtiles, 512, 0, stream>>>(fb16, w1b, z, N);
  aggregate<<<E, 128, 0, stream>>>(edges, nidx, z, M2, out, E);
}

// Round 9
// 203.718 us; speedup vs baseline: 1.0698x; 1.0698x over previous
//
#include <hip/hip_runtime.h>
#include <hip/hip_bf16.h>

// Shapes (fixed by the reference):
//   edges [E=4096,2] i32 | neigh_idx [N=1e5,K=10] i32 | features [N,256] f32
//   W1 [128,256] | W2 [128,128] | Wc [2,128] f32 -> out [E,2] f32
//
// Restructure: z = features @ W1^T (bf16 MFMA); per-edge 2-hop mean/relu/mean
// on z rows; classifier folded to M2 = Wc@W2.
//
// R9: re-fuse conversion into gemm_z (R8 showed the fcvt split's extra
//     51MB write + 51MB read ate the staging win). Keep the R8 lesson:
//     staging must be DEEP — batch all 8 float4 loads into registers
//     (issue-then-convert), not load-convert-write interleaved (R5's
//     VGPR=52 shallow pipeline, 63.9us, MfmaUtil 3.7%).

typedef __bf16 bf16x8 __attribute__((ext_vector_type(8)));
typedef float f32x4 __attribute__((ext_vector_type(4)));

#define FEAT 256
#define EMB  128
#define KNB  10
#define BM   64    // gemm M-tile rows; LDS = 64*(256+8)*2B = 33.8 KB

__device__ inline unsigned short f2b(float f) {
  unsigned int u = __float_as_uint(f);
  unsigned int r = (u + 0x7fffu + ((u >> 16) & 1u)) >> 16;  // RNE
  return (unsigned short)r;
}
__device__ inline float b2f(unsigned int s) {
  return __uint_as_float(s << 16);
}

// ---- gemm_z: z = feat @ W1^T (bf16 MFMA, f32 accum, bf16 out) -----------
// 512 threads (8 waves), BM=64 rows/block. Wave w owns cols [16w,16w+16).
// Staging phase 1: 8 batched global float4 loads -> registers (deep MLP).
// Staging phase 2: convert f32->bf16, ds_write_b64 into padded LDS.
// Last block computes M2 = Wc@W2 instead.

__global__ __launch_bounds__(512, 4) void gemm_z(
    const float* __restrict__ feat, const float* __restrict__ W1,
    const float* __restrict__ W2, const float* __restrict__ Wc,
    unsigned short* __restrict__ z, float* __restrict__ M2, int M) {
  __shared__ unsigned short As[BM][FEAT + 8];   // stride 528B: 16B-aligned rows,
                                                // frag reads 2-way (free), writes 4-way

  if (blockIdx.x == gridDim.x - 1) {
    // M2 = Wc @ W2 -> [2,128] f32
    int t = threadIdx.x;
    if (t < 256) {
      int c = t >> 7, d = t & 127;
      float s = 0.f;
      for (int g = 0; g < EMB; ++g) s += Wc[c * EMB + g] * W2[g * EMB + d];
      M2[t] = s;
    }
    return;
  }

  const int tid  = threadIdx.x;
  const int wid  = tid >> 6;
  const int lane = tid & 63;
  const int m0   = blockIdx.x * BM;

  // B fragments: lane holds col=(lane&15), k = kk*32 + (lane>>4)*8 + i
  const int col = wid * 16 + (lane & 15);
  const int kof = (lane >> 4) * 8;
  bf16x8 bfrag[8];
#pragma unroll
  for (int kk = 0; kk < 8; ++kk) {
    const float* src = &W1[col * FEAT + kk * 32 + kof];
    float4 lo = *reinterpret_cast<const float4*>(src);
    float4 hi = *reinterpret_cast<const float4*>(src + 4);
    union { unsigned short s[8]; bf16x8 v; } cvt;
    cvt.s[0] = f2b(lo.x); cvt.s[1] = f2b(lo.y); cvt.s[2] = f2b(lo.z); cvt.s[3] = f2b(lo.w);
    cvt.s[4] = f2b(hi.x); cvt.s[5] = f2b(hi.y); cvt.s[6] = f2b(hi.z); cvt.s[7] = f2b(hi.w);
    bfrag[kk] = cvt.v;
  }

  // ---- A staging, phase 1: batch-issue 8 float4 loads (32 VGPRs in flight)
  const float4* f4 = reinterpret_cast<const float4*>(feat);
  float4 v[8];
#pragma unroll
  for (int i = 0; i < 8; ++i) {
    int c  = tid + 512 * i;         // chunk id over BM*64 = 4096 chunks
    int r  = c >> 6, c4 = c & 63;   // 64 chunks (of 4 f32) per row
    int row = m0 + r;
    v[i] = make_float4(0.f, 0.f, 0.f, 0.f);
    if (row < M) v[i] = f4[(size_t)row * 64 + c4];
  }
  // ---- phase 2: convert + LDS write
#pragma unroll
  for (int i = 0; i < 8; ++i) {
    int c = tid + 512 * i;
    int r = c >> 6, c4 = c & 63;
    ushort4 bq;
    bq.x = f2b(v[i].x); bq.y = f2b(v[i].y); bq.z = f2b(v[i].z); bq.w = f2b(v[i].w);
    *reinterpret_cast<ushort4*>(&As[r][c4 * 4]) = bq;
  }
  __syncthreads();

  f32x4 acc[BM / 16] = {};
  const int arow = lane & 15;
  const int q    = lane >> 4;
#pragma unroll
  for (int mt = 0; mt < BM / 16; ++mt) {
#pragma unroll
    for (int kk = 0; kk < 8; ++kk) {
      bf16x8 a = *reinterpret_cast<const bf16x8*>(&As[mt * 16 + arow][kk * 32 + kof]);
      acc[mt] = __builtin_amdgcn_mfma_f32_16x16x32_bf16(a, bfrag[kk], acc[mt], 0, 0, 0);
    }
  }

  // D layout: col = lane&15, row = (lane>>4)*4 + reg   [m89-verified]
#pragma unroll
  for (int mt = 0; mt < BM / 16; ++mt) {
    int rbase = m0 + mt * 16 + q * 4;
#pragma unroll
    for (int r = 0; r < 4; ++r) {
      int row = rbase + r;
      if (row < M) z[(size_t)row * EMB + col] = f2b(acc[mt][r]);
    }
  }
}

// ---- per-edge aggregation + classifier (unchanged from R3/R8) -----------

__global__ __launch_bounds__(128) void aggregate(
    const int* __restrict__ edges, const int* __restrict__ nidx,
    const unsigned short* __restrict__ z, const float* __restrict__ M2,
    float* __restrict__ out, int E) {
  __shared__ int   s_idx2[2][KNB];
  __shared__ int   s_idx1[2][KNB * KNB];
  __shared__ float s_pm[2][EMB];

  const int e = blockIdx.x;
  const int t = threadIdx.x;
  const int w = t >> 6;
  const int l = t & 63;
  const int h = l >> 5;
  const int q = l & 31;

  if (t < 2 * KNB) {
    int p = t / KNB, k = t % KNB;
    int v = edges[e * 2 + p];
    s_idx2[p][k] = nidx[(size_t)v * KNB + k];
  }
  __syncthreads();
  for (int i = t; i < 2 * KNB * KNB; i += 128) {
    int p = i / 100, r = i % 100;
    s_idx1[p][r] = nidx[(size_t)s_idx2[p][r / KNB] * KNB + (r % KNB)];
  }
  __syncthreads();

  float pooled[4] = {0.f, 0.f, 0.f, 0.f};
#pragma unroll
  for (int k = 0; k < KNB; ++k) {
    float a[4] = {0.f, 0.f, 0.f, 0.f};
#pragma unroll
    for (int jp = 0; jp < KNB / 2; ++jp) {
      int u = s_idx1[w][k * KNB + jp * 2 + h];
      uint2 v = *reinterpret_cast<const uint2*>(&z[(size_t)u * EMB + q * 4]);
      a[0] += b2f(v.x & 0xffffu); a[1] += b2f(v.x >> 16);
      a[2] += b2f(v.y & 0xffffu); a[3] += b2f(v.y >> 16);
    }
#pragma unroll
    for (int c = 0; c < 4; ++c) {
      float s = a[c] + __shfl_xor(a[c], 32);   // combine row parities: 10-row sum
      pooled[c] += fmaxf(s * 0.1f, 0.f);       // relu(mean_j)
    }
  }
  if (h == 0) {
#pragma unroll
    for (int c = 0; c < 4; ++c) s_pm[w][q * 4 + c] = pooled[c] * 0.1f;  // mean_k
  }
  __syncthreads();

  if (w == 0) {
    int d0 = 2 * l, d1 = 2 * l + 1;
    float p0 = 0.5f * (s_pm[0][d0] + s_pm[1][d0]);
    float p1 = 0.5f * (s_pm[0][d1] + s_pm[1][d1]);
    float s0 = p0 * M2[d0]       + p1 * M2[d1];
    float s1 = p0 * M2[EMB + d0] + p1 * M2[EMB + d1];
#pragma unroll
    for (int off = 32; off > 0; off >>= 1) {
      s0 += __shfl_down(s0, off);
      s1 += __shfl_down(s1, off);
    }
    if (l == 0) { out[e * 2 + 0] = s0; out[e * 2 + 1] = s1; }
  }
}

// ---- launcher -----------------------------------------------------------

extern "C" void kernel_launch(void* const* d_in, const int* in_sizes, int n_in,
                              void* d_out, int out_size, void* d_ws, size_t ws_size,
                              hipStream_t stream) {
  const int*   edges = (const int*)d_in[0];
  const int*   nidx  = (const int*)d_in[1];
  const float* feat  = (const float*)d_in[2];
  const float* W1    = (const float*)d_in[3];
  const float* W2    = (const float*)d_in[4];
  const float* Wc    = (const float*)d_in[5];
  float* out = (float*)d_out;

  const int N = in_sizes[2] / FEAT;   // 100000
  const int E = in_sizes[0] / 2;      // 4096

  char* ws = (char*)d_ws;
  unsigned short* z = (unsigned short*)ws;                         // N*128 bf16
  float* M2 = (float*)(ws + (size_t)N * EMB * sizeof(unsigned short));

  const int mtiles = (N + BM - 1) / BM;   // 1563
  gemm_z   <<<mtiles + 1, 512, 0, stream>>>(feat, W1, W2, Wc, z, M2, N);
  aggregate<<<E, 128, 0, stream>>>(edges, nidx, z, M2, out, E);
}